// Round 5
// baseline (910.234 us; speedup 1.0000x reference)
//
#include <hip/hip_runtime.h>

#define NNODES 65536
#define NEDGES 1048576
#define NGRAPH 64
#define NPERG  1024
#define KEEP   512
#define M2     (NGRAPH * KEEP)   // 32768
#define HD     128
#define NC     10

// canonical weight block offsets (floats)
#define OW1 0
#define OW2 16384
#define OWL 32768
#define OB1 34048
#define OB2 34176
#define OP  34304
#define OBL 34432
#define NCVT 34448

__device__ __forceinline__ float bf2f(unsigned short u) {
    return __uint_as_float(((unsigned int)u) << 16);
}
__device__ __forceinline__ unsigned short f2bf(float f) {
    unsigned int u = __float_as_uint(f);
    unsigned int r = (u + 0x7FFFu + ((u >> 16) & 1u)) >> 16;
    return (unsigned short)r;
}

// ---------------- dtype detector: 1 = bf16 storage, 0 = fp32 storage ---------
// Samples even-index ushorts of W1 (16384 elems). bf16 data: ~100% have
// exponent in [100,140]. fp32 data: even ushorts are low mantissa bits ->
// ~16% in range.
__global__ void detect_kernel(const unsigned short* __restrict__ w1u, int* __restrict__ flag) {
    __shared__ int cnt;
    int t = threadIdx.x;  // 256
    if (t == 0) cnt = 0;
    __syncthreads();
    int local = 0;
    for (int i = t; i < 512; i += 256) {
        unsigned short u = w1u[2 * i];
        int e = (u >> 7) & 0xFF;
        if (e >= 100 && e <= 140) local++;
    }
    atomicAdd(&cnt, local);
    __syncthreads();
    if (t == 0) flag[0] = (cnt >= 384) ? 1 : 0;
}

// ---------------- canonicalize small weights to fp32 -------------------------
__global__ void cvt_kernel(const void* __restrict__ W1, const void* __restrict__ b1,
                           const void* __restrict__ p, const void* __restrict__ W2,
                           const void* __restrict__ b2, const void* __restrict__ Wl,
                           const void* __restrict__ bl, const int* __restrict__ flag,
                           float* __restrict__ out) {
    int gid = blockIdx.x * 256 + threadIdx.x;
    if (gid >= NCVT) return;
    const void* srcp; int idx;
    if (gid < OB1) {
        if (gid < OW2)      { srcp = W1; idx = gid - OW1; }
        else if (gid < OWL) { srcp = W2; idx = gid - OW2; }
        else                { srcp = Wl; idx = gid - OWL; }
    } else {
        if (gid < OB2)      { srcp = b1; idx = gid - OB1; }
        else if (gid < OP)  { srcp = b2; idx = gid - OB2; }
        else if (gid < OBL) { srcp = p;  idx = gid - OP; }
        else                { srcp = bl; idx = gid - OBL; }
    }
    if (gid >= OWL && gid < OB1 && idx >= 1280) { out[gid] = 0.f; return; }   // Wl pad
    if (gid >= OBL && idx >= NC) { out[gid] = 0.f; return; }                  // bl pad
    float v;
    if (flag[0]) v = bf2f(((const unsigned short*)srcp)[idx]);
    else         v = ((const float*)srcp)[idx];
    out[gid] = v;
}

// ---------------- init: deg=0, new_id=-1 -------------------------------------
__global__ void init_kernel(int* __restrict__ deg1, int* __restrict__ deg2,
                            int* __restrict__ new_id) {
    int i = blockIdx.x * 256 + threadIdx.x;  // NNODES threads
    deg1[i] = 0;
    new_id[i] = -1;
    if (i < M2) deg2[i] = 0;
}

// ---------------- GEMM1: C[M,128] = A(flagged dtype)[M,128] @ W[128,128] -----
__global__ __launch_bounds__(256) void gemm_a_kernel(const void* __restrict__ Araw,
                                                     const float* __restrict__ W,
                                                     float* __restrict__ C,
                                                     const int* __restrict__ flag) {
    __shared__ float As[64 * HD];  // 32 KB
    int tid = threadIdx.x;
    int row0 = blockIdx.x * 64;
    if (flag[0]) {
        const unsigned short* Au = (const unsigned short*)Araw + (size_t)row0 * HD;
        for (int i = tid; i < 64 * HD; i += 256) As[i] = bf2f(Au[i]);
    } else {
        const float* Af = (const float*)Araw + (size_t)row0 * HD;
        for (int i = tid; i < 64 * HD / 4; i += 256)
            reinterpret_cast<float4*>(As)[i] = reinterpret_cast<const float4*>(Af)[i];
    }
    __syncthreads();
    int cg = tid & 31;   // cols 4*cg .. 4*cg+3
    int rg = tid >> 5;   // rows 8*rg .. 8*rg+7
    float acc[8][4];
#pragma unroll
    for (int r = 0; r < 8; r++)
#pragma unroll
        for (int c = 0; c < 4; c++) acc[r][c] = 0.f;
    for (int k = 0; k < HD; k++) {
        float4 wv = reinterpret_cast<const float4*>(W + k * HD)[cg];
#pragma unroll
        for (int r = 0; r < 8; r++) {
            float av = As[(rg * 8 + r) * HD + k];
            acc[r][0] += av * wv.x;
            acc[r][1] += av * wv.y;
            acc[r][2] += av * wv.z;
            acc[r][3] += av * wv.w;
        }
    }
#pragma unroll
    for (int r = 0; r < 8; r++) {
        float4 o = {acc[r][0], acc[r][1], acc[r][2], acc[r][3]};
        reinterpret_cast<float4*>(C + (size_t)(row0 + rg * 8 + r) * HD)[cg] = o;
    }
}

// ---------------- GEMM (fp32 A) for conv2 ------------------------------------
__global__ __launch_bounds__(256) void gemm_f32(const float* __restrict__ A,
                                                const float* __restrict__ W,
                                                float* __restrict__ C) {
    __shared__ float As[64 * HD];
    int tid = threadIdx.x;
    int row0 = blockIdx.x * 64;
    for (int i = tid; i < 64 * HD / 4; i += 256)
        reinterpret_cast<float4*>(As)[i] =
            reinterpret_cast<const float4*>(A + (size_t)row0 * HD)[i];
    __syncthreads();
    int cg = tid & 31;
    int rg = tid >> 5;
    float acc[8][4];
#pragma unroll
    for (int r = 0; r < 8; r++)
#pragma unroll
        for (int c = 0; c < 4; c++) acc[r][c] = 0.f;
    for (int k = 0; k < HD; k++) {
        float4 wv = reinterpret_cast<const float4*>(W + k * HD)[cg];
#pragma unroll
        for (int r = 0; r < 8; r++) {
            float av = As[(rg * 8 + r) * HD + k];
            acc[r][0] += av * wv.x;
            acc[r][1] += av * wv.y;
            acc[r][2] += av * wv.z;
            acc[r][3] += av * wv.w;
        }
    }
#pragma unroll
    for (int r = 0; r < 8; r++) {
        float4 o = {acc[r][0], acc[r][1], acc[r][2], acc[r][3]};
        reinterpret_cast<float4*>(C + (size_t)(row0 + rg * 8 + r) * HD)[cg] = o;
    }
}

// ---------------- p-norm -----------------------------------------------------
__global__ void pnorm_kernel(const float* __restrict__ p, float* __restrict__ invnorm) {
    int t = threadIdx.x;  // 128
    float v = p[t];
    v = v * v;
    for (int off = 32; off; off >>= 1) v += __shfl_down(v, off);
    __shared__ float s[2];
    if ((t & 63) == 0) s[t >> 6] = v;
    __syncthreads();
    if (t == 0) invnorm[0] = 1.0f / sqrtf(s[0] + s[1]);
}

// ---------------- degree / dinv ----------------------------------------------
__global__ void deg1_kernel(const int* __restrict__ dst, int* __restrict__ deg) {
    int e = blockIdx.x * 256 + threadIdx.x;
    atomicAdd(&deg[dst[e]], 1);
}
__global__ void deg2_kernel(const int* __restrict__ src, const int* __restrict__ dst,
                            const int* __restrict__ new_id, int* __restrict__ deg) {
    int e = blockIdx.x * 256 + threadIdx.x;
    int ns = new_id[src[e]], nd = new_id[dst[e]];
    if ((ns | nd) >= 0) atomicAdd(&deg[nd], 1);
}
__global__ void dinv_kernel(const int* __restrict__ deg, float* __restrict__ dinv) {
    int i = blockIdx.x * 256 + threadIdx.x;
    dinv[i] = rsqrtf((float)deg[i] + 1.0f);
}

// ---------------- self-loop init: agg = dinv^2 * xw + b ----------------------
__global__ void selfinit_kernel(const float* __restrict__ xw, const float* __restrict__ dinv,
                                const float* __restrict__ bias, float* __restrict__ agg) {
    int gid = blockIdx.x * 256 + threadIdx.x;
    int row = gid >> 7, c = gid & 127;
    float di = dinv[row];
    agg[gid] = di * di * xw[gid] + bias[c];
}

// ---------------- edge scatter (wave per edge, 128 channels) -----------------
__global__ __launch_bounds__(256) void scatter1_kernel(
    const int* __restrict__ src, const int* __restrict__ dst, const float* __restrict__ dinv,
    const float* __restrict__ xw, float* __restrict__ agg) {
    int gid = blockIdx.x * 256 + threadIdx.x;
    int e = gid >> 6, lane = gid & 63;
    int s = src[e], d = dst[e];
    float coef = dinv[s] * dinv[d];
    const float* xs = xw + (size_t)s * HD;
    float* ad = agg + (size_t)d * HD;
    atomicAdd(ad + lane, coef * xs[lane]);
    atomicAdd(ad + lane + 64, coef * xs[lane + 64]);
}
__global__ __launch_bounds__(256) void scatter2_kernel(
    const int* __restrict__ src, const int* __restrict__ dst, const int* __restrict__ new_id,
    const float* __restrict__ dinv2, const float* __restrict__ xw2, float* __restrict__ agg2) {
    int gid = blockIdx.x * 256 + threadIdx.x;
    int e = gid >> 6, lane = gid & 63;
    int ns = new_id[src[e]], nd = new_id[dst[e]];
    if ((ns | nd) < 0) return;
    float coef = dinv2[ns] * dinv2[nd];
    const float* xs = xw2 + (size_t)ns * HD;
    float* ad = agg2 + (size_t)nd * HD;
    atomicAdd(ad + lane, coef * xs[lane]);
    atomicAdd(ad + lane + 64, coef * xs[lane + 64]);
}

// ---------------- relu in place ----------------------------------------------
__global__ void relu_kernel(float* __restrict__ x) {
    int gid = blockIdx.x * 256 + threadIdx.x;
    float4 v = reinterpret_cast<float4*>(x)[gid];
    v.x = fmaxf(v.x, 0.f); v.y = fmaxf(v.y, 0.f);
    v.z = fmaxf(v.z, 0.f); v.w = fmaxf(v.w, 0.f);
    reinterpret_cast<float4*>(x)[gid] = v;
}

// ---------------- score = tanh(h.p * invnorm) --------------------------------
__global__ __launch_bounds__(256) void score_kernel(const float* __restrict__ h,
                                                    const float* __restrict__ p,
                                                    const float* __restrict__ invnorm,
                                                    float* __restrict__ score) {
    int gid = blockIdx.x * 256 + threadIdx.x;
    int row = gid >> 6, lane = gid & 63;
    float v = h[(size_t)row * HD + lane] * p[lane] +
              h[(size_t)row * HD + lane + 64] * p[lane + 64];
    for (int off = 32; off; off >>= 1) v += __shfl_down(v, off);
    if (lane == 0) score[row] = tanhf(v * invnorm[0]);
}

// ---------------- per-graph top-512 via bitonic sort of 1024 -----------------
__global__ __launch_bounds__(1024) void topk_kernel(const float* __restrict__ score,
                                                    float* __restrict__ vals,
                                                    int* __restrict__ perm,
                                                    int* __restrict__ new_id) {
    __shared__ float sv[1024];
    __shared__ int si[1024];
    int g = blockIdx.x, t = threadIdx.x;
    sv[t] = score[g * NPERG + t];
    si[t] = t;
    __syncthreads();
    for (int k = 2; k <= 1024; k <<= 1) {
        for (int j = k >> 1; j > 0; j >>= 1) {
            int l = t ^ j;
            if (l > t) {
                bool desc = ((t & k) == 0);
                float va = sv[t], vb = sv[l];
                int ia = si[t], ib = si[l];
                bool gab = (va > vb) || (va == vb && ia < ib);  // lax.top_k tie rule
                if (gab != desc) { sv[t] = vb; si[t] = ib; sv[l] = va; si[l] = ia; }
            }
            __syncthreads();
        }
    }
    if (t < KEEP) {
        int node = g * NPERG + si[t];
        int slot = g * KEEP + t;
        vals[slot] = sv[t];
        perm[slot] = node;
        new_id[node] = slot;
    }
}

// ---------------- gather + gate (fp32) ---------------------------------------
__global__ void gather_kernel(const float* __restrict__ h, const int* __restrict__ perm,
                              const float* __restrict__ vals, float* __restrict__ h2) {
    int gid = blockIdx.x * 256 + threadIdx.x;
    int i = gid >> 7, c = gid & 127;
    h2[gid] = h[(size_t)perm[i] * HD + c] * vals[i];
}

// ---------------- mean-pool + linear; output dtype follows flag --------------
__global__ __launch_bounds__(512) void pool_kernel(const float* __restrict__ h3,
                                                   const float* __restrict__ Wl,
                                                   const float* __restrict__ bl,
                                                   void* __restrict__ outv,
                                                   const int* __restrict__ flag) {
    int g = blockIdx.x, t = threadIdx.x;  // 512
    int c = t & 127, rg = t >> 7;
    const float* base = h3 + (size_t)g * KEEP * HD;
    float sum = 0.f;
    for (int k = rg; k < KEEP; k += 4) sum += base[(size_t)k * HD + c];
    __shared__ float sp[4][128];
    sp[rg][c] = sum;
    __syncthreads();
    if (t < 128) sp[0][t] = (sp[0][t] + sp[1][t] + sp[2][t] + sp[3][t]) * (1.0f / KEEP);
    __syncthreads();
    if (t < NC) {
        float acc = bl[t];
        for (int hh = 0; hh < HD; hh++) acc += sp[0][hh] * Wl[hh * NC + t];
        if (flag[0]) ((unsigned short*)outv)[g * NC + t] = f2bf(acc);
        else         ((float*)outv)[g * NC + t] = acc;
    }
}

extern "C" void kernel_launch(void* const* d_in, const int* in_sizes, int n_in,
                              void* d_out, int out_size, void* d_ws, size_t ws_size,
                              hipStream_t stream) {
    const int* ei   = (const int*)d_in[1];
    const int* srcv = ei;
    const int* dstv = ei + NEDGES;

    char* w = (char*)d_ws;
    const size_t MB = 1u << 20;
    float* dinv1   = (float*)(w + 0);
    float* score   = (float*)(w + 256 * 1024);
    float* vals    = (float*)(w + 512 * 1024);
    int*   perm    = (int*)(w + 640 * 1024);
    int*   new_id  = (int*)(w + 768 * 1024);
    int*   deg1    = (int*)(w + 1024 * 1024);
    int*   deg2i   = (int*)(w + 1280 * 1024);
    float* dinv2   = (float*)(w + 1408 * 1024);
    float* invnorm = (float*)(w + 1536 * 1024);
    int*   flag    = (int*)(w + 1536 * 1024 + 64);
    float* cw      = (float*)(w + 1664 * 1024);   // canonical fp32 weights (NCVT floats)
    float* xw1  = (float*)(w + 2 * MB);           // [2,34) MB
    float* agg  = (float*)(w + 34 * MB);          // [34,66) MB   (h)
    float* h2   = (float*)(w + 2 * MB);           // [2,18) MB    (xw1 dead)
    float* xw2  = (float*)(w + 18 * MB);          // [18,34) MB   (xw1 dead)
    float* agg2 = (float*)(w + 34 * MB);          // [34,50) MB   (h dead)

    float* W1f = cw + OW1; float* W2f = cw + OW2; float* Wlf = cw + OWL;
    float* b1f = cw + OB1; float* b2f = cw + OB2; float* pf  = cw + OP;
    float* blf = cw + OBL;

    detect_kernel<<<1, 256, 0, stream>>>((const unsigned short*)d_in[3], flag);
    cvt_kernel<<<(NCVT + 255) / 256, 256, 0, stream>>>(d_in[3], d_in[4], d_in[5], d_in[6],
                                                       d_in[7], d_in[8], d_in[9], flag, cw);
    init_kernel<<<NNODES / 256, 256, 0, stream>>>(deg1, deg2i, new_id);
    pnorm_kernel<<<1, 128, 0, stream>>>(pf, invnorm);
    // conv1
    gemm_a_kernel<<<NNODES / 64, 256, 0, stream>>>(d_in[0], W1f, xw1, flag);
    deg1_kernel<<<NEDGES / 256, 256, 0, stream>>>(dstv, deg1);
    dinv_kernel<<<NNODES / 256, 256, 0, stream>>>(deg1, dinv1);
    selfinit_kernel<<<NNODES * HD / 256, 256, 0, stream>>>(xw1, dinv1, b1f, agg);
    scatter1_kernel<<<NEDGES / 4, 256, 0, stream>>>(srcv, dstv, dinv1, xw1, agg);
    relu_kernel<<<NNODES * HD / 4 / 256, 256, 0, stream>>>(agg);
    // top-k pooling
    score_kernel<<<NNODES / 4, 256, 0, stream>>>(agg, pf, invnorm, score);
    topk_kernel<<<NGRAPH, 1024, 0, stream>>>(score, vals, perm, new_id);
    gather_kernel<<<M2 * HD / 256, 256, 0, stream>>>(agg, perm, vals, h2);
    // conv2
    gemm_f32<<<M2 / 64, 256, 0, stream>>>(h2, W2f, xw2);
    deg2_kernel<<<NEDGES / 256, 256, 0, stream>>>(srcv, dstv, new_id, deg2i);
    dinv_kernel<<<M2 / 256, 256, 0, stream>>>(deg2i, dinv2);
    selfinit_kernel<<<M2 * HD / 256, 256, 0, stream>>>(xw2, dinv2, b2f, agg2);
    scatter2_kernel<<<NEDGES / 4, 256, 0, stream>>>(srcv, dstv, new_id, dinv2, xw2, agg2);
    relu_kernel<<<M2 * HD / 4 / 256, 256, 0, stream>>>(agg2);
    // readout
    pool_kernel<<<NGRAPH, 512, 0, stream>>>(agg2, Wlf, blf, d_out, flag);

    (void)in_sizes; (void)n_in; (void)out_size; (void)ws_size;
}